// Round 22
// baseline (92.096 us; speedup 1.0000x reference)
//
#include <hip/hip_runtime.h>
#include <hip/hip_bf16.h>

typedef __attribute__((ext_vector_type(16))) float f32x16;
typedef __attribute__((ext_vector_type(8)))  int   i32x8;
typedef __attribute__((ext_vector_type(4)))  int   i32x4;

static constexpr int NROW = 8192;
static constexpr int DDIM = 512;
static constexpr float INV_T = 10.0f;    // 1 / temperature
static constexpr float SHIFT = 70.0f;    // fixed logsumexp shift (logit max ~60)
// exp(acc*10 - 70) = exp2(acc*14.4269504 - 100.98865)
static constexpr float E2_SC = 14.4269504089f;
static constexpr float E2_BI = -100.988652759f;
static constexpr unsigned SCALE1 = 0x7F7F7F7Fu;   // e8m0 = 127 -> 2^0 = 1.0

__device__ __forceinline__ void gload_lds16(const void* gsrc, void* ldst) {
  __builtin_amdgcn_global_load_lds(
      (const __attribute__((address_space(1))) unsigned int*)gsrc,
      (__attribute__((address_space(3))) unsigned int*)ldst, 16, 0, 0);
}

// single-instruction v_exp_f32 (arg range here is [-187,-14]: no edge cases)
__device__ __forceinline__ float fast_exp2(float x) {
#if __has_builtin(__builtin_amdgcn_exp2f)
  return __builtin_amdgcn_exp2f(x);
#else
  float r;
  asm("v_exp_f32 %0, %1" : "=v"(r) : "v"(x));
  return r;
#endif
}

// pack 4 floats into 4 fp8 e4m3 bytes (gfx950: OCP encoding)
__device__ __forceinline__ unsigned int pack_fp8x4(float x, float y, float z, float w) {
  unsigned int r = 0;
  r = __builtin_amdgcn_cvt_pk_fp8_f32(x, y, r, false);  // bytes 0,1
  r = __builtin_amdgcn_cvt_pk_fp8_f32(z, w, r, true);   // bytes 2,3
  return r;
}

// ---------- prep: normalize anchors, cast to fp8, EXACT fp32 diagonal ----------
__global__ void prep_kernel(const float* __restrict__ f0,
                            const float* __restrict__ f1,
                            unsigned int* __restrict__ A,   // [NROW][DDIM] fp8
                            unsigned int* __restrict__ B,
                            float* __restrict__ wsS,        // [NROW] exp-sums (zeroed)
                            float* __restrict__ wsPosRow) { // [NROW] exact pos_i
  int gid  = blockIdx.x * blockDim.x + threadIdx.x;
  if (gid < NROW) wsS[gid] = 0.f;             // zero LSE accumulators
  int wid  = gid >> 6;                         // one wave per row
  int lane = threadIdx.x & 63;
  const float4* s0 = (const float4*)(f0 + (size_t)wid * (2 * DDIM));  // features[:,0,:]
  const float4* s1 = (const float4*)(f1 + (size_t)wid * (2 * DDIM));  // features1[:,0,:]
  float4 v0 = s0[lane], v1 = s0[lane + 64];
  float4 w0 = s1[lane], w1 = s1[lane + 64];
  float ss = v0.x * v0.x + v0.y * v0.y + v0.z * v0.z + v0.w * v0.w +
             v1.x * v1.x + v1.y * v1.y + v1.z * v1.z + v1.w * v1.w;
  float cc = v0.x * w0.x + v0.y * w0.y + v0.z * w0.z + v0.w * w0.w +
             v1.x * w1.x + v1.y * w1.y + v1.z * w1.z + v1.w * w1.w;
#pragma unroll
  for (int m = 1; m < 64; m <<= 1) {
    ss += __shfl_xor(ss, m);
    cc += __shfl_xor(cc, m);
  }
  float rn = rsqrtf(ss);
  if (lane == 0) wsPosRow[wid] = cc * rn * INV_T;   // exact fp32 diagonal logit
  A[wid * 128 + lane]      = pack_fp8x4(v0.x * rn, v0.y * rn, v0.z * rn, v0.w * rn);
  A[wid * 128 + 64 + lane] = pack_fp8x4(v1.x * rn, v1.y * rn, v1.z * rn, v1.w * rn);
  B[wid * 128 + lane]      = pack_fp8x4(w0.x, w0.y, w0.z, w0.w);
  B[wid * 128 + 64 + lane] = pack_fp8x4(w1.x, w1.y, w1.z, w1.w);
}

// ---------- fused S = A.B^T / T with fixed-shift LSE accumulation ----------
// OCCUPANCY ROUND. r18-r21 ran ~1 wave/SIMD (Occupancy ~10%): the 64 KB
// double-buffer capped residency at <=2 blocks/CU and grid 512 delivered ~1.
// Per SIMD that left ~800 cyc of issue in an ~8000-cyc tile slot — 75% pure
// exposed latency. This round: SINGLE 32 KB buffer (5 blocks/CU LDS-wise) and
// grid 1024 (32 row panels x 32 col splits, 4 tiles each) = 4 blocks/CU =
// 4 waves/SIMD. The stage stall inside each block is covered by the other
// blocks' MFMA/VALU (m114 TLP mechanism) — the thing dbuf never achieved.
// Everything else verbatim r20: MX 32x32x64 scales=1.0, M_wave=64 dual-chain,
// hoisted carry-free addressing, raw v_exp_f32, setprio, (256,1) reg class.
__global__ __launch_bounds__(256, 1) void sim_lse_kernel(
    const unsigned char* __restrict__ Ag,
    const unsigned char* __restrict__ Bg,
    float* __restrict__ wsS) {
  __shared__ __align__(16) char buf[64 * 512];    // 32 KiB single B-tile

  const int tid  = threadIdx.x;
  const int w    = tid >> 6;                 // wave 0..3
  const int lane = tid & 63;
  const int lr5  = lane & 31;                // row (A) / col (B,D) within 32
  const int h    = lane >> 5;                // k-half selector (32 B each)

  const int p  = blockIdx.x >> 5;            // row panel 0..31 (256 rows)
  const int cs = blockIdx.x & 31;            // col split 0..31 (256 cols)
  const int r0 = p * 256 + w * 64;           // this wave's first row (64 rows)
  const int c0 = cs * 256;                   // first column of this split

  // staging: 8 iters; iter it stages row-pair pr = it*4 + w (rows 2pr+h);
  // src byte ((lane&31)<<4) ^ ((n&7)<<4), n&7 = (2w+h)&7 -> per-thread const.
  const int stg_off = ((lane & 31) << 4) ^ (((2 * w + h) & 7) << 4);
  const int stg_row = h;
  const int swz = (lr5 & 7) << 4;

  // A fragments, K-resident, 2 row-blocks:
  // aX[ks] = 32 B of A[r0+X*32+lr5][ks*64 + h*32 .. +32)
  i32x8 a0[8], a1[8];
  {
    const char* ar0 = (const char*)Ag + (size_t)(r0 + lr5) * DDIM + h * 32;
    const char* ar1 = (const char*)Ag + (size_t)(r0 + 32 + lr5) * DDIM + h * 32;
#pragma unroll
    for (int ks = 0; ks < 8; ks++) {
      a0[ks] = *(const i32x8*)(ar0 + ks * 64);
      a1[ks] = *(const i32x8*)(ar1 + ks * 64);
    }
  }

  float sums0[16], sums1[16];
#pragma unroll
  for (int r = 0; r < 16; r++) { sums0[r] = 0.f; sums1[r] = 0.f; }

#define STAGE(T)                                                               \
  {                                                                            \
    const char* gb = (const char*)Bg + (size_t)(c0 + (T) * 64) * DDIM;         \
    _Pragma("unroll")                                                          \
    for (int it = 0; it < 8; it++) {                                           \
      int pr = it * 4 + w;                                                     \
      gload_lds16(gb + (size_t)(2 * pr + stg_row) * DDIM + stg_off,            \
                  buf + pr * 1024);                                            \
    }                                                                          \
  }

// One jb-chunk: 8-MFMA dual chain + immediate epilogue (r20 form).
// ks = 2m+e: addr = base_e + m*128 (carry-free XOR decomposition).
#define MFMA_EPI()                                                             \
  {                                                                            \
    _Pragma("unroll")                                                          \
    for (int jb = 0; jb < 2; jb++) {                                           \
      const int cb = ((jb * 32 + lr5) * 512 + h * 32) ^ swz;                   \
      const char* p0  = buf + cb;                                              \
      const char* p0x = buf + (cb ^ 16);                                       \
      const char* p1  = buf + (cb ^ 64);                                       \
      const char* p1x = buf + (cb ^ 80);                                       \
      f32x16 acc0 = (f32x16){0.f};                                             \
      f32x16 acc1 = (f32x16){0.f};                                             \
      __builtin_amdgcn_s_setprio(1);                                           \
      _Pragma("unroll")                                                        \
      for (int m = 0; m < 4; m++) {                                            \
        i32x8 bvE = __builtin_shufflevector(                                   \
            *(const i32x4*)(p0 + m * 128), *(const i32x4*)(p0x + m * 128),     \
            0, 1, 2, 3, 4, 5, 6, 7);                                           \
        i32x8 bvO = __builtin_shufflevector(                                   \
            *(const i32x4*)(p1 + m * 128), *(const i32x4*)(p1x + m * 128),     \
            0, 1, 2, 3, 4, 5, 6, 7);                                           \
        acc0 = __builtin_amdgcn_mfma_scale_f32_32x32x64_f8f6f4(                \
            a0[2 * m], bvE, acc0, 0, 0, 0, SCALE1, 0, SCALE1);                 \
        acc1 = __builtin_amdgcn_mfma_scale_f32_32x32x64_f8f6f4(                \
            a1[2 * m], bvE, acc1, 0, 0, 0, SCALE1, 0, SCALE1);                 \
        acc0 = __builtin_amdgcn_mfma_scale_f32_32x32x64_f8f6f4(                \
            a0[2 * m + 1], bvO, acc0, 0, 0, 0, SCALE1, 0, SCALE1);             \
        acc1 = __builtin_amdgcn_mfma_scale_f32_32x32x64_f8f6f4(                \
            a1[2 * m + 1], bvO, acc1, 0, 0, 0, SCALE1, 0, SCALE1);             \
      }                                                                        \
      __builtin_amdgcn_s_setprio(0);                                           \
      _Pragma("unroll")                                                        \
      for (int r = 0; r < 16; r++) {                                           \
        sums0[r] += fast_exp2(fmaf(acc0[r], E2_SC, E2_BI));                    \
        sums1[r] += fast_exp2(fmaf(acc1[r], E2_SC, E2_BI));                    \
      }                                                                        \
    }                                                                          \
  }

  STAGE(0);
  __syncthreads();                            // tile 0 ready

#pragma unroll 1
  for (int t = 0; t < 4; t++) {
    MFMA_EPI();                               // compute tile t
    if (t < 3) {
      __syncthreads();                        // all waves done reading buf
      STAGE(t + 1);
      __syncthreads();                        // tile t+1 ready
    }
  }

#undef STAGE
#undef MFMA_EPI

  // reduce over the 32 col-partition lanes; lanes lr5==0 (h=0,1) commit rows
#pragma unroll
  for (int r = 0; r < 16; r++) {
    float s0 = sums0[r], s1 = sums1[r];
    s0 += __shfl_xor(s0, 1);  s1 += __shfl_xor(s1, 1);
    s0 += __shfl_xor(s0, 2);  s1 += __shfl_xor(s1, 2);
    s0 += __shfl_xor(s0, 4);  s1 += __shfl_xor(s1, 4);
    s0 += __shfl_xor(s0, 8);  s1 += __shfl_xor(s1, 8);
    s0 += __shfl_xor(s0, 16); s1 += __shfl_xor(s1, 16);
    if (lr5 == 0) {
      int rr = (r & 3) + 8 * (r >> 2) + 4 * h;
      atomicAdd(&wsS[r0 + rr], s0);
      atomicAdd(&wsS[r0 + 32 + rr], s1);
    }
  }
}

// ---------- finalize: loss = mean(SHIFT + log(S_r) - pos_r) ----------
__global__ void finalize_kernel(const float* __restrict__ wsS,
                                const float* __restrict__ wsPosRow,
                                float* __restrict__ out) {
  __shared__ float red[16];
  float part = 0.f;
  for (int r = threadIdx.x; r < NROW; r += 1024)
    part += SHIFT + __logf(wsS[r]) - wsPosRow[r];
#pragma unroll
  for (int m = 1; m < 64; m <<= 1) part += __shfl_xor(part, m);
  if ((threadIdx.x & 63) == 0) red[threadIdx.x >> 6] = part;
  __syncthreads();
  if (threadIdx.x < 16) {
    float t = red[threadIdx.x];
#pragma unroll
    for (int m = 1; m < 16; m <<= 1) t += __shfl_xor(t, m);
    if (threadIdx.x == 0) out[0] = t / (float)NROW;
  }
}

extern "C" void kernel_launch(void* const* d_in, const int* in_sizes, int n_in,
                              void* d_out, int out_size, void* d_ws, size_t ws_size,
                              hipStream_t stream) {
  const float* f0 = (const float*)d_in[0];
  const float* f1 = (const float*)d_in[1];
  // d_in[2] (y) is unused by the reference computation.

  unsigned char* A = (unsigned char*)d_ws;                         // 4 MiB fp8
  unsigned char* B = A + (size_t)NROW * DDIM;                      // 4 MiB fp8
  float* wsS      = (float*)(B + (size_t)NROW * DDIM);             // [NROW]
  float* wsPosRow = wsS + NROW;                                    // [NROW]

  prep_kernel<<<NROW / 4, 256, 0, stream>>>(f0, f1, (unsigned int*)A,
                                            (unsigned int*)B, wsS, wsPosRow);
  sim_lse_kernel<<<1024, 256, 0, stream>>>(A, B, wsS);
  finalize_kernel<<<1, 1024, 0, stream>>>(wsS, wsPosRow, (float*)d_out);
}

// Round 23
// 54.953 us; speedup vs baseline: 1.6759x; 1.6759x over previous
//
#include <hip/hip_runtime.h>
#include <hip/hip_bf16.h>

typedef __attribute__((ext_vector_type(4)))  float f32x4;
typedef __attribute__((ext_vector_type(8)))  int   i32x8;
typedef __attribute__((ext_vector_type(4)))  int   i32x4;

static constexpr int NROW = 8192;
static constexpr int DDIM = 512;
static constexpr float INV_T = 10.0f;    // 1 / temperature
static constexpr float SHIFT = 70.0f;    // fixed logsumexp shift (logit max ~60)
// exp(acc*10 - 70) = exp2(acc*14.4269504 - 100.98865)
static constexpr float E2_SC = 14.4269504089f;
static constexpr float E2_BI = -100.988652759f;
static constexpr unsigned SCALE1 = 0x7F7F7F7Fu;   // e8m0 = 127 -> 2^0 = 1.0

__device__ __forceinline__ void gload_lds16(const void* gsrc, void* ldst) {
  __builtin_amdgcn_global_load_lds(
      (const __attribute__((address_space(1))) unsigned int*)gsrc,
      (__attribute__((address_space(3))) unsigned int*)ldst, 16, 0, 0);
}

// single-instruction v_exp_f32 (arg range here is [-187,-14]: no edge cases)
__device__ __forceinline__ float fast_exp2(float x) {
#if __has_builtin(__builtin_amdgcn_exp2f)
  return __builtin_amdgcn_exp2f(x);
#else
  float r;
  asm("v_exp_f32 %0, %1" : "=v"(r) : "v"(x));
  return r;
#endif
}

// pack 4 floats into 4 fp8 e4m3 bytes (gfx950: OCP encoding)
__device__ __forceinline__ unsigned int pack_fp8x4(float x, float y, float z, float w) {
  unsigned int r = 0;
  r = __builtin_amdgcn_cvt_pk_fp8_f32(x, y, r, false);  // bytes 0,1
  r = __builtin_amdgcn_cvt_pk_fp8_f32(z, w, r, true);   // bytes 2,3
  return r;
}

// ---------- prep: normalize anchors, cast to fp8, EXACT fp32 diagonal ----------
__global__ void prep_kernel(const float* __restrict__ f0,
                            const float* __restrict__ f1,
                            unsigned int* __restrict__ A,   // [NROW][DDIM] fp8
                            unsigned int* __restrict__ B,
                            float* __restrict__ wsS,        // [NROW] exp-sums (zeroed)
                            float* __restrict__ wsPosRow) { // [NROW] exact pos_i
  int gid  = blockIdx.x * blockDim.x + threadIdx.x;
  if (gid < NROW) wsS[gid] = 0.f;             // zero LSE accumulators
  int wid  = gid >> 6;                         // one wave per row
  int lane = threadIdx.x & 63;
  const float4* s0 = (const float4*)(f0 + (size_t)wid * (2 * DDIM));  // features[:,0,:]
  const float4* s1 = (const float4*)(f1 + (size_t)wid * (2 * DDIM));  // features1[:,0,:]
  float4 v0 = s0[lane], v1 = s0[lane + 64];
  float4 w0 = s1[lane], w1 = s1[lane + 64];
  float ss = v0.x * v0.x + v0.y * v0.y + v0.z * v0.z + v0.w * v0.w +
             v1.x * v1.x + v1.y * v1.y + v1.z * v1.z + v1.w * v1.w;
  float cc = v0.x * w0.x + v0.y * w0.y + v0.z * w0.z + v0.w * w0.w +
             v1.x * w1.x + v1.y * w1.y + v1.z * w1.z + v1.w * w1.w;
#pragma unroll
  for (int m = 1; m < 64; m <<= 1) {
    ss += __shfl_xor(ss, m);
    cc += __shfl_xor(cc, m);
  }
  float rn = rsqrtf(ss);
  if (lane == 0) wsPosRow[wid] = cc * rn * INV_T;   // exact fp32 diagonal logit
  A[wid * 128 + lane]      = pack_fp8x4(v0.x * rn, v0.y * rn, v0.z * rn, v0.w * rn);
  A[wid * 128 + 64 + lane] = pack_fp8x4(v1.x * rn, v1.y * rn, v1.z * rn, v1.w * rn);
  B[wid * 128 + lane]      = pack_fp8x4(w0.x, w0.y, w0.z, w0.w);
  B[wid * 128 + 64 + lane] = pack_fp8x4(w1.x, w1.y, w1.z, w1.w);
}

// ---------- fused S = A.B^T / T with fixed-shift LSE accumulation ----------
// MX-scaled fp8 16x16x128 (scales=1.0 == plain fp8 numerics; K-permutation-
// invariant since A and B use the IDENTICAL byte mapping — same argument that
// made 32x32x64 bit-correct on first try, r11). C/D: col=lane&15,
// row=(lane>>4)*4+reg (HW-verified m89, dtype-independent).
// WHY THIS SHAPE: the two session laws are (1) 512-thr blocks cap at 128
// VGPR, 256-thr gets 256; (2) resident waves/CU = ONE block's waves, always
// (occupancy 10.5% @256thr vs 20.5% @512thr across 22 rounds). So 2 waves/
// SIMD — the r8-proven latency hider — requires a 512-thr block that fits
// 128 VGPR. 16x16x128 at M_wave=32 needs only a0/a1[4] i32x8 = 64 regs +
// sums 8 + f32x4 accs (AGPR) ≈ 115 total, vs 32x32x64's ~180.
// r8's winning dbuf skeleton verbatim: grid 256 (32 panels x 8 cs, 16 tiles),
// stage(t+1) before MFMA(t), 1 barrier/tile, source-side XOR swizzle.
__global__ __launch_bounds__(512, 2) void sim_lse_kernel(
    const unsigned char* __restrict__ Ag,
    const unsigned char* __restrict__ Bg,
    float* __restrict__ wsS) {
  __shared__ __align__(16) char bufA[64 * 512];   // 32 KiB, tiles 0,2,4,...
  __shared__ __align__(16) char bufB[64 * 512];   // 32 KiB, tiles 1,3,5,...

  const int tid  = threadIdx.x;
  const int w    = tid >> 6;                 // wave 0..7
  const int lane = tid & 63;
  const int lr   = lane & 15;                // row (A) / col (B,D) within 16
  const int kg   = lane >> 4;                // k-group 0..3 (32 B each)

  const int p  = blockIdx.x >> 3;            // row panel 0..31 (256 rows)
  const int cs = blockIdx.x & 7;             // col split 0..7 (1024 cols)
  const int r0 = p * 256 + w * 32;           // this wave's first row (32 rows)
  const int c0 = cs * 1024;                  // first column of this split

  // staging (verbatim r8): wave w stages row-pairs pr = it*8+w; lane covers
  // 16 B of row n = 2*pr + (lane>>5); src byte ((lane&31)<<4) ^ ((n&7)<<4).
  const int h5      = lane >> 5;
  const int stg_off = ((lane & 31) << 4) ^ (((2 * w + h5) & 7) << 4);
  const int stg_row = h5;
  const int swz = (lr & 7) << 4;             // col&7 == lr&7 (16 | jb*16)

  // A fragments, K-resident, 2 row-blocks of 16:
  // aX[ks] = 32 B of A[r0 + X*16 + lr][ks*128 + kg*32 .. +32)
  i32x8 a0[4], a1[4];
  {
    const char* ar0 = (const char*)Ag + (size_t)(r0 + lr) * DDIM + kg * 32;
    const char* ar1 = (const char*)Ag + (size_t)(r0 + 16 + lr) * DDIM + kg * 32;
#pragma unroll
    for (int ks = 0; ks < 4; ks++) {
      a0[ks] = *(const i32x8*)(ar0 + ks * 128);
      a1[ks] = *(const i32x8*)(ar1 + ks * 128);
    }
  }

  float sums0[4], sums1[4];
#pragma unroll
  for (int r = 0; r < 4; r++) { sums0[r] = 0.f; sums1[r] = 0.f; }

#define STAGE(BUF, T)                                                          \
  {                                                                            \
    const char* gb = (const char*)Bg + (size_t)(c0 + (T) * 64) * DDIM;         \
    _Pragma("unroll")                                                          \
    for (int it = 0; it < 4; it++) {                                           \
      int pr = it * 8 + w;                                                     \
      gload_lds16(gb + (size_t)(2 * pr + stg_row) * DDIM + stg_off,            \
                  (char*)(BUF) + pr * 1024);                                   \
    }                                                                          \
  }

// One tile (64 cols = 4 jb of 16): per jb, 4 k-steps; B-frag shared by the
// two row-block chains (acc0/acc1 interleave = 2-chain ILP x 2 waves/SIMD).
#define MFMA_EPI(BUF)                                                          \
  {                                                                            \
    _Pragma("unroll")                                                          \
    for (int jb = 0; jb < 4; jb++) {                                           \
      const int cb = ((jb * 16 + lr) * 512 + kg * 32) ^ swz;                   \
      const char* p0  = (const char*)(BUF) + cb;                               \
      const char* p0x = (const char*)(BUF) + (cb ^ 16);                        \
      f32x4 acc0 = (f32x4){0.f, 0.f, 0.f, 0.f};                                \
      f32x4 acc1 = (f32x4){0.f, 0.f, 0.f, 0.f};                                \
      __builtin_amdgcn_s_setprio(1);                                           \
      _Pragma("unroll")                                                        \
      for (int ks = 0; ks < 4; ks++) {                                         \
        i32x8 bv = __builtin_shufflevector(                                    \
            *(const i32x4*)(p0 + ks * 128), *(const i32x4*)(p0x + ks * 128),   \
            0, 1, 2, 3, 4, 5, 6, 7);                                           \
        acc0 = __builtin_amdgcn_mfma_scale_f32_16x16x128_f8f6f4(               \
            a0[ks], bv, acc0, 0, 0, 0, SCALE1, 0, SCALE1);                     \
        acc1 = __builtin_amdgcn_mfma_scale_f32_16x16x128_f8f6f4(               \
            a1[ks], bv, acc1, 0, 0, 0, SCALE1, 0, SCALE1);                     \
      }                                                                        \
      __builtin_amdgcn_s_setprio(0);                                           \
      _Pragma("unroll")                                                        \
      for (int r = 0; r < 4; r++) {                                            \
        sums0[r] += fast_exp2(fmaf(acc0[r], E2_SC, E2_BI));                    \
        sums1[r] += fast_exp2(fmaf(acc1[r], E2_SC, E2_BI));                    \
      }                                                                        \
    }                                                                          \
  }

  STAGE(bufA, 0);
  __syncthreads();                            // tile 0 ready

#pragma unroll 1
  for (int t = 0; t < 16; t += 2) {
    STAGE(bufB, t + 1);                       // async; lands under MFMA below
    MFMA_EPI(bufA);                           // tile t
    __syncthreads();                          // readers of A done; B drained
    if (t + 2 < 16) STAGE(bufA, t + 2);       // async; lands under MFMA below
    MFMA_EPI(bufB);                           // tile t+1
    __syncthreads();
  }

#undef STAGE
#undef MFMA_EPI

  // reduce over the 16 col-partition lanes (same kg); lane lr==0 commits.
  // Lane's rows: r0 + rb*16 + kg*4 + r  (C/D row = (lane>>4)*4 + reg, m89).
#pragma unroll
  for (int r = 0; r < 4; r++) {
    float s0 = sums0[r], s1 = sums1[r];
    s0 += __shfl_xor(s0, 1);  s1 += __shfl_xor(s1, 1);
    s0 += __shfl_xor(s0, 2);  s1 += __shfl_xor(s1, 2);
    s0 += __shfl_xor(s0, 4);  s1 += __shfl_xor(s1, 4);
    s0 += __shfl_xor(s0, 8);  s1 += __shfl_xor(s1, 8);
    if (lr == 0) {
      atomicAdd(&wsS[r0 + kg * 4 + r], s0);
      atomicAdd(&wsS[r0 + 16 + kg * 4 + r], s1);
    }
  }
}

// ---------- finalize: loss = mean(SHIFT + log(S_r) - pos_r) ----------
__global__ void finalize_kernel(const float* __restrict__ wsS,
                                const float* __restrict__ wsPosRow,
                                float* __restrict__ out) {
  __shared__ float red[16];
  float part = 0.f;
  for (int r = threadIdx.x; r < NROW; r += 1024)
    part += SHIFT + __logf(wsS[r]) - wsPosRow[r];
#pragma unroll
  for (int m = 1; m < 64; m <<= 1) part += __shfl_xor(part, m);
  if ((threadIdx.x & 63) == 0) red[threadIdx.x >> 6] = part;
  __syncthreads();
  if (threadIdx.x < 16) {
    float t = red[threadIdx.x];
#pragma unroll
    for (int m = 1; m < 16; m <<= 1) t += __shfl_xor(t, m);
    if (threadIdx.x == 0) out[0] = t / (float)NROW;
  }
}

extern "C" void kernel_launch(void* const* d_in, const int* in_sizes, int n_in,
                              void* d_out, int out_size, void* d_ws, size_t ws_size,
                              hipStream_t stream) {
  const float* f0 = (const float*)d_in[0];
  const float* f1 = (const float*)d_in[1];
  // d_in[2] (y) is unused by the reference computation.

  unsigned char* A = (unsigned char*)d_ws;                         // 4 MiB fp8
  unsigned char* B = A + (size_t)NROW * DDIM;                      // 4 MiB fp8
  float* wsS      = (float*)(B + (size_t)NROW * DDIM);             // [NROW]
  float* wsPosRow = wsS + NROW;                                    // [NROW]

  prep_kernel<<<NROW / 4, 256, 0, stream>>>(f0, f1, (unsigned int*)A,
                                            (unsigned int*)B, wsS, wsPosRow);
  sim_lse_kernel<<<256, 512, 0, stream>>>(A, B, wsS);
  finalize_kernel<<<1, 1024, 0, stream>>>(wsS, wsPosRow, (float*)d_out);
}

// Round 24
// 48.945 us; speedup vs baseline: 1.8816x; 1.1228x over previous
//
#include <hip/hip_runtime.h>
#include <hip/hip_bf16.h>

typedef __attribute__((ext_vector_type(4)))  float f32x4;
typedef __attribute__((ext_vector_type(8)))  int   i32x8;
typedef __attribute__((ext_vector_type(4)))  int   i32x4;

static constexpr int NROW = 8192;
static constexpr int DDIM = 512;
static constexpr float INV_T = 10.0f;    // 1 / temperature
static constexpr float SHIFT = 70.0f;    // fixed logsumexp shift (logit max ~60)
// exp(acc*10 - 70) = exp2(acc*14.4269504 - 100.98865)
static constexpr float E2_SC = 14.4269504089f;
static constexpr float E2_BI = -100.988652759f;
static constexpr unsigned SCALE1 = 0x7F7F7F7Fu;   // e8m0 = 127 -> 2^0 = 1.0

__device__ __forceinline__ void gload_lds16(const void* gsrc, void* ldst) {
  __builtin_amdgcn_global_load_lds(
      (const __attribute__((address_space(1))) unsigned int*)gsrc,
      (__attribute__((address_space(3))) unsigned int*)ldst, 16, 0, 0);
}

// single-instruction v_exp_f32 (arg range here is [-187,-14]: no edge cases)
__device__ __forceinline__ float fast_exp2(float x) {
#if __has_builtin(__builtin_amdgcn_exp2f)
  return __builtin_amdgcn_exp2f(x);
#else
  float r;
  asm("v_exp_f32 %0, %1" : "=v"(r) : "v"(x));
  return r;
#endif
}

// pack 4 floats into 4 fp8 e4m3 bytes (gfx950: OCP encoding)
__device__ __forceinline__ unsigned int pack_fp8x4(float x, float y, float z, float w) {
  unsigned int r = 0;
  r = __builtin_amdgcn_cvt_pk_fp8_f32(x, y, r, false);  // bytes 0,1
  r = __builtin_amdgcn_cvt_pk_fp8_f32(z, w, r, true);   // bytes 2,3
  return r;
}

// ---------- prep: normalize anchors, cast to fp8, EXACT fp32 diagonal ----------
__global__ void prep_kernel(const float* __restrict__ f0,
                            const float* __restrict__ f1,
                            unsigned int* __restrict__ A,   // [NROW][DDIM] fp8
                            unsigned int* __restrict__ B,
                            float* __restrict__ wsS,        // [NROW] exp-sums (zeroed)
                            float* __restrict__ wsPosRow) { // [NROW] exact pos_i
  int gid  = blockIdx.x * blockDim.x + threadIdx.x;
  if (gid < NROW) wsS[gid] = 0.f;             // zero LSE accumulators
  int wid  = gid >> 6;                         // one wave per row
  int lane = threadIdx.x & 63;
  const float4* s0 = (const float4*)(f0 + (size_t)wid * (2 * DDIM));  // features[:,0,:]
  const float4* s1 = (const float4*)(f1 + (size_t)wid * (2 * DDIM));  // features1[:,0,:]
  float4 v0 = s0[lane], v1 = s0[lane + 64];
  float4 w0 = s1[lane], w1 = s1[lane + 64];
  float ss = v0.x * v0.x + v0.y * v0.y + v0.z * v0.z + v0.w * v0.w +
             v1.x * v1.x + v1.y * v1.y + v1.z * v1.z + v1.w * v1.w;
  float cc = v0.x * w0.x + v0.y * w0.y + v0.z * w0.z + v0.w * w0.w +
             v1.x * w1.x + v1.y * w1.y + v1.z * w1.z + v1.w * w1.w;
#pragma unroll
  for (int m = 1; m < 64; m <<= 1) {
    ss += __shfl_xor(ss, m);
    cc += __shfl_xor(cc, m);
  }
  float rn = rsqrtf(ss);
  if (lane == 0) wsPosRow[wid] = cc * rn * INV_T;   // exact fp32 diagonal logit
  A[wid * 128 + lane]      = pack_fp8x4(v0.x * rn, v0.y * rn, v0.z * rn, v0.w * rn);
  A[wid * 128 + 64 + lane] = pack_fp8x4(v1.x * rn, v1.y * rn, v1.z * rn, v1.w * rn);
  B[wid * 128 + lane]      = pack_fp8x4(w0.x, w0.y, w0.z, w0.w);
  B[wid * 128 + 64 + lane] = pack_fp8x4(w1.x, w1.y, w1.z, w1.w);
}

// ---------- fused S = A.B^T / T with fixed-shift LSE accumulation ----------
// r23 (16x16x128 MX, 2 waves/SIMD, 43.4 us) + T3/T4: TRI-buffer with counted
// vmcnt. __syncthreads drained vmcnt to 0 every tile — each wave waited the
// full L3/HBM latency of its just-issued t+1 loads, 16 times (the ~74%-stall
// signature). Now: prefetch depth 2; per tile {compute(t); STAGE(t+2);
// s_waitcnt vmcnt(4); s_barrier} — each wave has 4 own loads/STAGE, <=8
// outstanding, wait-to-4 => tile t+1 landed while t+2's loads STAY IN FLIGHT
// across the barrier (the never-drain-to-0 rule). Buffer rotation is fully
// static (period-3 hand-unroll). gload_lds is vmcnt-tracked; the "memory"
// clobber + raw s_barrier order the ds_reads. All math verbatim r23.
__global__ __launch_bounds__(512, 2) void sim_lse_kernel(
    const unsigned char* __restrict__ Ag,
    const unsigned char* __restrict__ Bg,
    float* __restrict__ wsS) {
  __shared__ __align__(16) char buf0[64 * 512];   // 32 KiB each; tiles t%3
  __shared__ __align__(16) char buf1[64 * 512];
  __shared__ __align__(16) char buf2[64 * 512];

  const int tid  = threadIdx.x;
  const int w    = tid >> 6;                 // wave 0..7
  const int lane = tid & 63;
  const int lr   = lane & 15;                // row (A) / col (B,D) within 16
  const int kg   = lane >> 4;                // k-group 0..3 (32 B each)

  const int p  = blockIdx.x >> 3;            // row panel 0..31 (256 rows)
  const int cs = blockIdx.x & 7;             // col split 0..7 (1024 cols)
  const int r0 = p * 256 + w * 32;           // this wave's first row (32 rows)
  const int c0 = cs * 1024;                  // first column of this split

  // staging (verbatim r8/r23): wave w stages row-pairs pr = it*8+w; lane
  // covers 16 B of row n = 2*pr + (lane>>5); src byte ((lane&31)<<4)^((n&7)<<4)
  const int h5      = lane >> 5;
  const int stg_off = ((lane & 31) << 4) ^ (((2 * w + h5) & 7) << 4);
  const int stg_row = h5;
  const int swz = (lr & 7) << 4;             // col&7 == lr&7 (16 | jb*16)

  // A fragments, K-resident, 2 row-blocks of 16:
  // aX[ks] = 32 B of A[r0 + X*16 + lr][ks*128 + kg*32 .. +32)
  i32x8 a0[4], a1[4];
  {
    const char* ar0 = (const char*)Ag + (size_t)(r0 + lr) * DDIM + kg * 32;
    const char* ar1 = (const char*)Ag + (size_t)(r0 + 16 + lr) * DDIM + kg * 32;
#pragma unroll
    for (int ks = 0; ks < 4; ks++) {
      a0[ks] = *(const i32x8*)(ar0 + ks * 128);
      a1[ks] = *(const i32x8*)(ar1 + ks * 128);
    }
  }

  float sums0[4], sums1[4];
#pragma unroll
  for (int r = 0; r < 4; r++) { sums0[r] = 0.f; sums1[r] = 0.f; }

#define STAGE(BUF, T)                                                          \
  {                                                                            \
    const char* gb = (const char*)Bg + (size_t)(c0 + (T) * 64) * DDIM;         \
    _Pragma("unroll")                                                          \
    for (int it = 0; it < 4; it++) {                                           \
      int pr = it * 8 + w;                                                     \
      gload_lds16(gb + (size_t)(2 * pr + stg_row) * DDIM + stg_off,            \
                  (char*)(BUF) + pr * 1024);                                   \
    }                                                                          \
  }

// One tile (64 cols = 4 jb of 16): per jb, 4 k-steps; B-frag shared by the
// two row-block chains (acc0/acc1 interleave).
#define MFMA_EPI(BUF)                                                          \
  {                                                                            \
    _Pragma("unroll")                                                          \
    for (int jb = 0; jb < 4; jb++) {                                           \
      const int cb = ((jb * 16 + lr) * 512 + kg * 32) ^ swz;                   \
      const char* p0  = (const char*)(BUF) + cb;                               \
      const char* p0x = (const char*)(BUF) + (cb ^ 16);                        \
      f32x4 acc0 = (f32x4){0.f, 0.f, 0.f, 0.f};                                \
      f32x4 acc1 = (f32x4){0.f, 0.f, 0.f, 0.f};                                \
      __builtin_amdgcn_s_setprio(1);                                           \
      _Pragma("unroll")                                                        \
      for (int ks = 0; ks < 4; ks++) {                                         \
        i32x8 bv = __builtin_shufflevector(                                    \
            *(const i32x4*)(p0 + ks * 128), *(const i32x4*)(p0x + ks * 128),   \
            0, 1, 2, 3, 4, 5, 6, 7);                                           \
        acc0 = __builtin_amdgcn_mfma_scale_f32_16x16x128_f8f6f4(               \
            a0[ks], bv, acc0, 0, 0, 0, SCALE1, 0, SCALE1);                     \
        acc1 = __builtin_amdgcn_mfma_scale_f32_16x16x128_f8f6f4(               \
            a1[ks], bv, acc1, 0, 0, 0, SCALE1, 0, SCALE1);                     \
      }                                                                        \
      __builtin_amdgcn_s_setprio(0);                                           \
      _Pragma("unroll")                                                        \
      for (int r = 0; r < 4; r++) {                                            \
        sums0[r] += fast_exp2(fmaf(acc0[r], E2_SC, E2_BI));                    \
        sums1[r] += fast_exp2(fmaf(acc1[r], E2_SC, E2_BI));                    \
      }                                                                        \
    }                                                                          \
  }

// counted-vmcnt barrier: own t+1 loads done, t+2's stay in flight.
#define WAITBAR4()                                                             \
  {                                                                            \
    asm volatile("s_waitcnt vmcnt(4)" ::: "memory");                           \
    __builtin_amdgcn_s_barrier();                                              \
  }
#define WAITBAR0()                                                             \
  {                                                                            \
    asm volatile("s_waitcnt vmcnt(0)" ::: "memory");                           \
    __builtin_amdgcn_s_barrier();                                              \
  }

  STAGE(buf0, 0);
  STAGE(buf1, 1);
  WAITBAR4();                                 // tile 0 landed; tile 1 in flight

#pragma unroll 1
  for (int i = 0; i < 4; i++) {               // tiles 3i .. 3i+2
    const int t = 3 * i;
    MFMA_EPI(buf0);  STAGE(buf2, t + 2);  WAITBAR4();
    MFMA_EPI(buf1);  STAGE(buf0, t + 3);  WAITBAR4();
    MFMA_EPI(buf2);  STAGE(buf1, t + 4);  WAITBAR4();
  }
  // tiles 12..15 (tiles 12,13 already staged by the loop)
  MFMA_EPI(buf0);  STAGE(buf2, 14);  WAITBAR4();
  MFMA_EPI(buf1);  STAGE(buf0, 15);  WAITBAR4();
  MFMA_EPI(buf2);  WAITBAR0();                // drain tile 15
  MFMA_EPI(buf0);

#undef STAGE
#undef MFMA_EPI
#undef WAITBAR4
#undef WAITBAR0

  // reduce over the 16 col-partition lanes (same kg); lane lr==0 commits.
  // Lane's rows: r0 + rb*16 + kg*4 + r  (C/D row = (lane>>4)*4 + reg, m89).
#pragma unroll
  for (int r = 0; r < 4; r++) {
    float s0 = sums0[r], s1 = sums1[r];
    s0 += __shfl_xor(s0, 1);  s1 += __shfl_xor(s1, 1);
    s0 += __shfl_xor(s0, 2);  s1 += __shfl_xor(s1, 2);
    s0 += __shfl_xor(s0, 4);  s1 += __shfl_xor(s1, 4);
    s0 += __shfl_xor(s0, 8);  s1 += __shfl_xor(s1, 8);
    if (lr == 0) {
      atomicAdd(&wsS[r0 + kg * 4 + r], s0);
      atomicAdd(&wsS[r0 + 16 + kg * 4 + r], s1);
    }
  }
}

// ---------- finalize: loss = mean(SHIFT + log(S_r) - pos_r) ----------
__global__ void finalize_kernel(const float* __restrict__ wsS,
                                const float* __restrict__ wsPosRow,
                                float* __restrict__ out) {
  __shared__ float red[16];
  float part = 0.f;
  for (int r = threadIdx.x; r < NROW; r += 1024)
    part += SHIFT + __logf(wsS[r]) - wsPosRow[r];
#pragma unroll
  for (int m = 1; m < 64; m <<= 1) part += __shfl_xor(part, m);
  if ((threadIdx.x & 63) == 0) red[threadIdx.x >> 6] = part;
  __syncthreads();
  if (threadIdx.x < 16) {
    float t = red[threadIdx.x];
#pragma unroll
    for (int m = 1; m < 16; m <<= 1) t += __shfl_xor(t, m);
    if (threadIdx.x == 0) out[0] = t / (float)NROW;
  }
}

extern "C" void kernel_launch(void* const* d_in, const int* in_sizes, int n_in,
                              void* d_out, int out_size, void* d_ws, size_t ws_size,
                              hipStream_t stream) {
  const float* f0 = (const float*)d_in[0];
  const float* f1 = (const float*)d_in[1];
  // d_in[2] (y) is unused by the reference computation.

  unsigned char* A = (unsigned char*)d_ws;                         // 4 MiB fp8
  unsigned char* B = A + (size_t)NROW * DDIM;                      // 4 MiB fp8
  float* wsS      = (float*)(B + (size_t)NROW * DDIM);             // [NROW]
  float* wsPosRow = wsS + NROW;                                    // [NROW]

  prep_kernel<<<NROW / 4, 256, 0, stream>>>(f0, f1, (unsigned int*)A,
                                            (unsigned int*)B, wsS, wsPosRow);
  sim_lse_kernel<<<256, 512, 0, stream>>>(A, B, wsS);
  finalize_kernel<<<1, 1024, 0, stream>>>(wsS, wsPosRow, (float*)d_out);
}